// Round 16
// baseline (695.831 us; speedup 1.0000x reference)
//
#include <hip/hip_runtime.h>
#include <hip/hip_bf16.h>
#include <stdint.h>

typedef __hip_bfloat16 bf16;

__device__ __forceinline__ float b2f(bf16 v){ return __bfloat162float(v); }

__device__ __forceinline__ uint16_t f2b(float x){           // RNE f32->bf16
  uint32_t u = __float_as_uint(x);
  return (uint16_t)((u + 0x7FFFu + ((u >> 16) & 1u)) >> 16);
}

__device__ __forceinline__ float loadf(const void* p, int j, bool isb){
  return isb ? b2f(((const bf16*)p)[j]) : ((const float*)p)[j];
}

#define DSTS_PER_BKT 128
#define BKT_SHIFT 7
#define CHUNKE 8192          // edges per bin block (BIN_IT*256)
#define CAP 8192             // LDS sort capacity (single chunk for mean bucket 4092)
#define PPT 32               // payloads per thread in register permute (CAP/256)
#define BIN_IT 32            // edges per thread in bin pass
#define MAXB 1024            // max buckets per graph
#define NBLKMAX 512          // max edge-chunks per graph
#define ROWS_PER_WAVE (DSTS_PER_BKT / 4)

// ---------------------------------------------------------------------------
// Detect whether float inputs are bf16 (flag=1) or f32 (flag=0).
// ---------------------------------------------------------------------------
__global__ __launch_bounds__(256) void k_detect(const void* __restrict__ sample,
                                                int* __restrict__ flag)
{
  __shared__ int bad;
  if (threadIdx.x == 0) bad = 0;
  __syncthreads();
  const unsigned short* u = (const unsigned short*)sample;
  int lbad = 0;
  for (int k = threadIdx.x; k < 1024; k += 256) {
    unsigned short b = u[k];
    unsigned e = (b >> 7) & 0xFFu;
    if (e >= 141u || (e <= 90u && (b & 0x7FFFu) != 0)) lbad = 1;
  }
  if (lbad) atomicOr(&bad, 1);
  __syncthreads();
  if (threadIdx.x == 0) flag[0] = (bad == 0) ? 1 : 0;
}

// ---------------------------------------------------------------------------
// Per-node prep with INLINE dtype conversion: f linears, h = f @ Wg,
// attention coefs, self-loop init of den/agg (f32), bf16 gather tables.
// Softmax without max-shift (logits bounded -> identical).
// ---------------------------------------------------------------------------
__global__ __launch_bounds__(256) void k_node(
  const void* __restrict__ rFp, const void* __restrict__ rFa,
  const void* __restrict__ rWp, const void* __restrict__ rbp,
  const void* __restrict__ rWa, const void* __restrict__ rba,
  const void* __restrict__ rWs, const void* __restrict__ rbs,
  const void* __restrict__ rWg0, const void* __restrict__ rAs0, const void* __restrict__ rAd0,
  const void* __restrict__ rWg1, const void* __restrict__ rAs1, const void* __restrict__ rAd1,
  const void* __restrict__ rWg2, const void* __restrict__ rAs2, const void* __restrict__ rAd2,
  const int* __restrict__ flag,
  uint32_t* __restrict__ hgb, uint16_t* __restrict__ asb, float* __restrict__ a_d,
  float* __restrict__ den, float* __restrict__ agg, int N)
{
  __shared__ float sWs[14*32];
  __shared__ float sWp[3*32];
  __shared__ float sWa[11*32];
  __shared__ float sb[3][32];
  __shared__ float sWg[3][32*32];
  __shared__ float sA[3][2][32];
  const int tid = threadIdx.x;
  const bool isb = (*flag) != 0;
  for (int t = tid; t < 14*32; t += 256) sWs[t] = loadf(rWs, t, isb);
  for (int t = tid; t < 3*32;  t += 256) sWp[t] = loadf(rWp, t, isb);
  for (int t = tid; t < 11*32; t += 256) sWa[t] = loadf(rWa, t, isb);
  if (tid < 32) {
    sb[0][tid] = loadf(rbs, tid, isb);
    sb[1][tid] = loadf(rbp, tid, isb);
    sb[2][tid] = loadf(rba, tid, isb);
    sA[0][0][tid] = loadf(rAs0, tid, isb); sA[0][1][tid] = loadf(rAd0, tid, isb);
    sA[1][0][tid] = loadf(rAs1, tid, isb); sA[1][1][tid] = loadf(rAd1, tid, isb);
    sA[2][0][tid] = loadf(rAs2, tid, isb); sA[2][1][tid] = loadf(rAd2, tid, isb);
  }
  for (int t = tid; t < 32*32; t += 256) {
    sWg[0][t] = loadf(rWg0, t, isb);
    sWg[1][t] = loadf(rWg1, t, isb);
    sWg[2][t] = loadf(rWg2, t, isb);
  }
  __syncthreads();

  const int i = blockIdx.x * 256 + tid;
  if (i >= N) return;

  float xp[3], xa[11];
  #pragma unroll
  for (int k = 0; k < 3; ++k)  xp[k] = loadf(rFp, i*3 + k, isb);
  #pragma unroll
  for (int k = 0; k < 11; ++k) xa[k] = loadf(rFa, i*11 + k, isb);

  for (int g = 0; g < 3; ++g) {
    float f[32];
    if (g == 0) {
      #pragma unroll
      for (int j = 0; j < 32; ++j) {
        float acc = sb[0][j];
        #pragma unroll
        for (int k = 0; k < 3; ++k)  acc += xp[k] * sWs[k*32 + j];
        #pragma unroll
        for (int k = 0; k < 11; ++k) acc += xa[k] * sWs[(3+k)*32 + j];
        f[j] = acc;
      }
    } else if (g == 1) {
      #pragma unroll
      for (int j = 0; j < 32; ++j) {
        float acc = sb[1][j];
        #pragma unroll
        for (int k = 0; k < 3; ++k) acc += xp[k] * sWp[k*32 + j];
        f[j] = acc;
      }
    } else {
      #pragma unroll
      for (int j = 0; j < 32; ++j) {
        float acc = sb[2][j];
        #pragma unroll
        for (int k = 0; k < 11; ++k) acc += xa[k] * sWa[k*32 + j];
        f[j] = acc;
      }
    }

    const float* Wg = sWg[g];
    float hv[32];
    #pragma unroll
    for (int j = 0; j < 32; ++j) {
      float acc = 0.f;
      #pragma unroll
      for (int k = 0; k < 32; ++k) acc += f[k] * Wg[k*32 + j];
      hv[j] = acc;
    }

    float asv[4], adv[4], exv[4];
    #pragma unroll
    for (int h = 0; h < 4; ++h) {
      float s0 = 0.f, s1 = 0.f;
      #pragma unroll
      for (int c = 0; c < 8; ++c) {
        s0 += hv[h*8 + c] * sA[g][0][h*8 + c];
        s1 += hv[h*8 + c] * sA[g][1][h*8 + c];
      }
      asv[h] = s0; adv[h] = s1;
      float e = s0 + s1;
      e = e > 0.f ? e : 0.2f * e;
      exv[h] = __expf(e);
    }

    const size_t row = (size_t)g * N + i;
    uint32_t* hp = hgb + row * 16;
    #pragma unroll
    for (int q = 0; q < 4; ++q) {
      uint4 u;
      u.x = (uint32_t)f2b(hv[q*8+0]) | ((uint32_t)f2b(hv[q*8+1]) << 16);
      u.y = (uint32_t)f2b(hv[q*8+2]) | ((uint32_t)f2b(hv[q*8+3]) << 16);
      u.z = (uint32_t)f2b(hv[q*8+4]) | ((uint32_t)f2b(hv[q*8+5]) << 16);
      u.w = (uint32_t)f2b(hv[q*8+6]) | ((uint32_t)f2b(hv[q*8+7]) << 16);
      *(uint4*)(hp + q*4) = u;
    }
    *(ushort4*)(asb + row * 4) =
        make_ushort4(f2b(asv[0]), f2b(asv[1]), f2b(asv[2]), f2b(asv[3]));

    float4* agp = (float4*)(agg + row * 32);
    #pragma unroll
    for (int q = 0; q < 8; ++q) {
      float ex = exv[q >> 1];
      agp[q] = make_float4(ex*hv[q*4+0], ex*hv[q*4+1], ex*hv[q*4+2], ex*hv[q*4+3]);
    }
    *(float4*)(a_d + row*4) = make_float4(adv[0], adv[1], adv[2], adv[3]);
    *(float4*)(den + row*4) = make_float4(exv[0], exv[1], exv[2], exv[3]);
  }
}

// ---------------------------------------------------------------------------
// Binning v2 — block-major, full-line writes only, zero global atomics.
// ---------------------------------------------------------------------------
__global__ __launch_bounds__(256) void k_bin2(
  const int* __restrict__ ei0, const int* __restrict__ ei1, const int* __restrict__ ei2,
  int* __restrict__ dir, int* __restrict__ bins, int NBPG, int NBLK, int E)
{
  const int g = blockIdx.y;
  const int* __restrict__ ei = (g == 0) ? ei0 : (g == 1 ? ei1 : ei2);
  __shared__ int sp[CHUNKE];            // 32 KB staged payloads
  __shared__ int hist[MAXB];
  __shared__ int soff[MAXB + 1];
  __shared__ int s[256];
  const int tid = threadIdx.x;
  const int blk = blockIdx.x;
  const int base = blk * CHUNKE;
  const int m = min(CHUNKE, E - base);

  for (int t = tid; t < NBPG; t += 256) hist[t] = 0;
  __syncthreads();

  int pk[BIN_IT];
  #pragma unroll
  for (int k = 0; k < BIN_IT; ++k) {
    int idx = base + k * 256 + tid;
    if (idx < E) {
      int d = ei[E + idx];
      int b = d >> BKT_SHIFT;
      int loc = atomicAdd(&hist[b], 1);
      pk[k] = (b << 20) | (loc << 7) | (d & (DSTS_PER_BKT - 1));
    } else pk[k] = -1;
  }
  __syncthreads();

  // exclusive scan hist -> soff
  {
    const int sb = tid * 4;
    int v[4]; int sum = 0;
    #pragma unroll
    for (int j = 0; j < 4; ++j) {
      int i = sb + j; int x = (i < NBPG) ? hist[i] : 0; v[j] = x; sum += x;
    }
    s[tid] = sum;
    __syncthreads();
    for (int d = 1; d < 256; d <<= 1) {
      int t = (tid >= d) ? s[tid - d] : 0;
      __syncthreads();
      s[tid] += t;
      __syncthreads();
    }
    int run = s[tid] - sum;
    #pragma unroll
    for (int j = 0; j < 4; ++j) {
      int i = sb + j;
      if (i < NBPG) { soff[i] = run; run += v[j]; }
    }
    if (tid == 255) soff[NBPG] = s[255];
  }
  __syncthreads();

  for (int t = tid; t <= NBPG; t += 256)
    dir[((size_t)(g * (NBPG + 1) + t)) * NBLK + blk] = soff[t];

  #pragma unroll
  for (int k = 0; k < BIN_IT; ++k) {
    int p = pk[k];
    if (p >= 0) {
      int idx = base + k * 256 + tid;
      int src = ei[idx];
      int b   = p >> 20;
      int loc = (p >> 7) & 0x1FFF;
      int dl  = p & (DSTS_PER_BKT - 1);
      sp[soff[b] + loc] = (dl << 17) | src;
    }
  }
  __syncthreads();

  const size_t ob = ((size_t)(g * NBLK + blk)) << 13;
  for (int i = tid; i < m; i += 256) bins[ob + i] = sp[i];
}

// ---------------------------------------------------------------------------
// Sorted gather, src-halved + XCD-affine: processes only edges whose src is
// in [hlo,hhi). Graph->XCD mapping via 1-D grid: xcd=bid&7 -> XCD 0-2: g0,
// 3-5: g1, 6-7: g2, so concurrent blocks on an XCD share ONE graph's hgb
// half-table (3.2MB < 4MB L2 -> resident). Two sequential passes cover all
// edges; agg/den accumulate across passes.
// ---------------------------------------------------------------------------
__global__ __launch_bounds__(256, 4) void k_vgather(
  const int* __restrict__ dir, const int* __restrict__ bins,
  const uint32_t* __restrict__ hgb, const uint16_t* __restrict__ asb,
  const float* __restrict__ a_d,
  float* __restrict__ den, float* __restrict__ agg,
  int NBPG, int NBLK, int N, int hlo, int hhi)
{
  __shared__ int sorted[CAP];                // 32 KB (stage + final, in place)
  __shared__ int runbase[NBLKMAX];
  __shared__ int pbase[NBLKMAX + 1];
  __shared__ int soff[DSTS_PER_BKT + 1];
  __shared__ int scnt[DSTS_PER_BKT];
  __shared__ int sscan[DSTS_PER_BKT];
  __shared__ int s[256];
  __shared__ int schunk;
  const int tid = threadIdx.x;
  // --- graph->XCD affinity mapping ---
  const int bid = blockIdx.x;
  const int xcd = bid & 7, slot = bid >> 3;
  int g, b;
  if (xcd < 3)      { g = 0; b = slot * 3 + xcd; }
  else if (xcd < 6) { g = 1; b = slot * 3 + (xcd - 3); }
  else              { g = 2; b = slot * 2 + (xcd - 6); }
  if (b >= NBPG) return;

  const int wave = tid >> 6;
  const int lane = tid & 63;
  const int sub  = lane >> 4;
  const int l16  = lane & 15;
  const int h    = l16 >> 2;
  const int grp16 = tid >> 4;
  const int ln16  = tid & 15;
  const size_t gbase = (size_t)g * N;
  const int dst0 = b * DSTS_PER_BKT;

  // --- setup: run directory for this bucket ---
  const int* d0 = dir + ((size_t)(g * (NBPG + 1) + b)) * NBLK;
  const int* d1 = d0 + NBLK;
  for (int t = tid; t < NBLK; t += 256) {
    int r0 = d0[t], r1 = d1[t];
    runbase[t] = ((g * NBLK + t) << 13) + r0;
    pbase[t] = r1 - r0;                       // temp: run lengths
  }
  __syncthreads();
  {
    int v0 = (2*tid     < NBLK) ? pbase[2*tid]     : 0;
    int v1 = (2*tid + 1 < NBLK) ? pbase[2*tid + 1] : 0;
    __syncthreads();
    int sum = v0 + v1; s[tid] = sum;
    __syncthreads();
    for (int d = 1; d < 256; d <<= 1) {
      int t = (tid >= d) ? s[tid - d] : 0;
      __syncthreads();
      s[tid] += t;
      __syncthreads();
    }
    int run = s[tid] - sum;
    if (2*tid     <= NBLK) pbase[2*tid]     = run;
    if (2*tid + 1 <= NBLK) pbase[2*tid + 1] = run + v0;
  }
  __syncthreads();
  const int ntot = pbase[NBLK];

  int rlo = 0;
  while (rlo < NBLK) {
    if (tid == 0) {
      if (rlo == 0 && ntot <= CAP) schunk = NBLK;
      else {
        int lim = pbase[rlo] + CAP;
        int hi = rlo + 1;
        while (hi < NBLK && pbase[hi + 1] <= lim) ++hi;
        schunk = hi;
      }
    }
    if (tid < DSTS_PER_BKT) scnt[tid] = 0;
    __syncthreads();
    const int rhi = schunk;
    const int pb0 = pbase[rlo];
    const int m = pbase[rhi] - pb0;

    // --- copy (stage all) + count (only in-half) ---
    for (int rr = rlo + grp16; rr < rhi; rr += 16) {
      const int l = pbase[rr + 1] - pbase[rr];
      const int gbb = runbase[rr];
      const int ldst = pbase[rr] - pb0;
      for (int i = ln16; i < l; i += 16) {
        int p = bins[gbb + i];
        sorted[ldst + i] = p;
        int src = p & 0x1FFFF;
        if (src >= hlo && src < hhi)
          atomicAdd(&scnt[(p >> 17) & (DSTS_PER_BKT - 1)], 1);
      }
    }
    __syncthreads();
    // scan scnt -> soff (filtered counts)
    if (tid < DSTS_PER_BKT) sscan[tid] = scnt[tid];
    __syncthreads();
    for (int d = 1; d < DSTS_PER_BKT; d <<= 1) {
      int t = 0;
      if (tid < DSTS_PER_BKT && tid >= d) t = sscan[tid - d];
      __syncthreads();
      if (tid < DSTS_PER_BKT) sscan[tid] += t;
      __syncthreads();
    }
    if (tid < DSTS_PER_BKT) {
      int ex = sscan[tid] - scnt[tid];
      soff[tid] = ex;
      scnt[tid] = ex;                          // scatter cursor
      if (tid == DSTS_PER_BKT - 1) soff[DSTS_PER_BKT] = sscan[tid];
    }
    __syncthreads();
    // --- in-place permute via registers (only in-half payloads) ---
    int pv[PPT];
    #pragma unroll
    for (int k = 0; k < PPT; ++k) {
      int i = k * 256 + tid;
      int p = (i < m) ? sorted[i] : -1;
      if (p >= 0) {
        int src = p & 0x1FFFF;
        if (src < hlo || src >= hhi) p = -1;
      }
      pv[k] = p;
    }
    __syncthreads();
    #pragma unroll
    for (int k = 0; k < PPT; ++k) {
      int p = pv[k];
      if (p >= 0) {
        int pos = atomicAdd(&scnt[(p >> 17) & (DSTS_PER_BKT - 1)], 1);
        sorted[pos] = p & 0x1FFFF;
      }
    }
    __syncthreads();

    // --- gather: wave-per-row, 16 edges in flight per step ---
    const int rbeg = wave * ROWS_PER_WAVE;
    for (int rl = rbeg; rl < rbeg + ROWS_PER_WAVE; ++rl) {
      const int dst = dst0 + rl;
      if (dst >= N) break;
      const int cs = soff[rl], ce = soff[rl + 1];
      const size_t row = gbase + dst;
      const float ad = a_d[row * 4 + h];
      float ax = 0.f, ay = 0.f, w = 0.f;
      for (int c = cs + sub; c < ce; c += 16) {
        const int i0 = c        < ce ? sorted[c]      : -1;
        const int i1 = (c + 4)  < ce ? sorted[c + 4]  : -1;
        const int i2 = (c + 8)  < ce ? sorted[c + 8]  : -1;
        const int i3 = (c + 12) < ce ? sorted[c + 12] : -1;
        const int p0 = i0 < 0 ? 0 : i0;
        const int p1 = i1 < 0 ? 0 : i1;
        const int p2 = i2 < 0 ? 0 : i2;
        const int p3 = i3 < 0 ? 0 : i3;
        const uint32_t u0 = hgb[(gbase + p0) * 16 + l16];
        const uint32_t u1 = hgb[(gbase + p1) * 16 + l16];
        const uint32_t u2 = hgb[(gbase + p2) * 16 + l16];
        const uint32_t u3 = hgb[(gbase + p3) * 16 + l16];
        const uint16_t t0 = asb[(gbase + p0) * 4 + h];
        const uint16_t t1 = asb[(gbase + p1) * 4 + h];
        const uint16_t t2 = asb[(gbase + p2) * 4 + h];
        const uint16_t t3 = asb[(gbase + p3) * 4 + h];
        float e0 = __uint_as_float((uint32_t)t0 << 16) + ad; e0 = e0 > 0.f ? e0 : 0.2f * e0;
        float e1 = __uint_as_float((uint32_t)t1 << 16) + ad; e1 = e1 > 0.f ? e1 : 0.2f * e1;
        float e2 = __uint_as_float((uint32_t)t2 << 16) + ad; e2 = e2 > 0.f ? e2 : 0.2f * e2;
        float e3 = __uint_as_float((uint32_t)t3 << 16) + ad; e3 = e3 > 0.f ? e3 : 0.2f * e3;
        const float w0 = i0 >= 0 ? __expf(e0) : 0.f;
        const float w1 = i1 >= 0 ? __expf(e1) : 0.f;
        const float w2 = i2 >= 0 ? __expf(e2) : 0.f;
        const float w3 = i3 >= 0 ? __expf(e3) : 0.f;
        ax += w0 * __uint_as_float(u0 << 16);
        ay += w0 * __uint_as_float(u0 & 0xFFFF0000u);
        ax += w1 * __uint_as_float(u1 << 16);
        ay += w1 * __uint_as_float(u1 & 0xFFFF0000u);
        ax += w2 * __uint_as_float(u2 << 16);
        ay += w2 * __uint_as_float(u2 & 0xFFFF0000u);
        ax += w3 * __uint_as_float(u3 << 16);
        ay += w3 * __uint_as_float(u3 & 0xFFFF0000u);
        w += w0 + w1 + w2 + w3;
      }
      ax += __shfl_xor(ax, 16); ay += __shfl_xor(ay, 16); w += __shfl_xor(w, 16);
      ax += __shfl_xor(ax, 32); ay += __shfl_xor(ay, 32); w += __shfl_xor(w, 32);
      if (sub == 0) {
        float2* ap = (float2*)(agg + row * 32) + l16;
        float2 sv = *ap;
        sv.x += ax; sv.y += ay;
        *ap = sv;
        if ((l16 & 3) == 0) den[row * 4 + h] += w;
      }
    }
    __syncthreads();
    rlo = rhi;
  }
}

// ---------------------------------------------------------------------------
// Final (inline weight conversion): normalize, +bias, ELU, concat -> MLP.
// ---------------------------------------------------------------------------
__global__ __launch_bounds__(256) void k_final(
  const float* __restrict__ den, const float* __restrict__ agg,
  const void* __restrict__ rbg0, const void* __restrict__ rbg1, const void* __restrict__ rbg2,
  const void* __restrict__ rW1, const void* __restrict__ rb1,
  const void* __restrict__ rW2, const void* __restrict__ rb2,
  const int* __restrict__ flag, void* __restrict__ out, int N)
{
  __shared__ float sW1[96*32];
  __shared__ float sW2[32*32];
  __shared__ float sb1[32], sb2[32], sbg[3][32];
  const int tid = threadIdx.x;
  const bool isb = (*flag) != 0;
  for (int t = tid; t < 96*32; t += 256) sW1[t] = loadf(rW1, t, isb);
  for (int t = tid; t < 32*32; t += 256) sW2[t] = loadf(rW2, t, isb);
  if (tid < 32) {
    sb1[tid] = loadf(rb1, tid, isb); sb2[tid] = loadf(rb2, tid, isb);
    sbg[0][tid] = loadf(rbg0, tid, isb);
    sbg[1][tid] = loadf(rbg1, tid, isb);
    sbg[2][tid] = loadf(rbg2, tid, isb);
  }
  __syncthreads();

  const int i = blockIdx.x * 256 + tid;
  if (i >= N) return;

  float h96[96];
  #pragma unroll
  for (int g = 0; g < 3; ++g) {
    const size_t row = (size_t)g * N + i;
    float4 d4 = *(const float4*)(den + row * 4);
    float invs[4] = {1.f/d4.x, 1.f/d4.y, 1.f/d4.z, 1.f/d4.w};
    const float4* av = (const float4*)(agg + row * 32);
    #pragma unroll
    for (int q = 0; q < 8; ++q) {
      float4 a4 = av[q];
      float iv = invs[q >> 1];
      float vals[4] = {a4.x, a4.y, a4.z, a4.w};
      #pragma unroll
      for (int k = 0; k < 4; ++k) {
        float v = vals[k] * iv + sbg[g][q*4 + k];
        v = v > 0.f ? v : (__expf(v) - 1.f);
        h96[g*32 + q*4 + k] = v;
      }
    }
  }

  float h1[32];
  #pragma unroll
  for (int j = 0; j < 32; ++j) {
    float acc = sb1[j];
    #pragma unroll
    for (int k = 0; k < 96; ++k) acc += h96[k] * sW1[k*32 + j];
    h1[j] = acc > 0.f ? acc : 0.f;
  }

  #pragma unroll
  for (int j = 0; j < 32; ++j) {
    float acc = sb2[j];
    #pragma unroll
    for (int k = 0; k < 32; ++k) acc += h1[k] * sW2[k*32 + j];
    if (isb) ((bf16*)out)[(size_t)i*32 + j] = __float2bfloat16(acc);
    else     ((float*)out)[(size_t)i*32 + j] = acc;
  }
}

// ---------------------------------------------------------------------------
extern "C" void kernel_launch(void* const* d_in, const int* in_sizes, int n_in,
                              void* d_out, int out_size, void* d_ws, size_t ws_size,
                              hipStream_t stream)
{
  const int N = in_sizes[0] / 3;     // F_p_raw is [N,3]
  const int E = in_sizes[2] / 2;     // edge_index is [2,E]
  const int NBPG = (N + DSTS_PER_BKT - 1) / DSTS_PER_BKT;
  const int NBLK = (E + CHUNKE - 1) / CHUNKE;
  const int SLOTS = (NBPG + 1) / 2;  // max slots per XCD (graph2 on 2 XCDs)
  const int mid = N >> 1;

  int* flag = (int*)d_ws;
  float* big = (float*)d_ws + 64;
  const size_t n3 = (size_t)3 * N;
  float* agg  = big;                          // n3*32 f32
  float* a_d  = agg + n3 * 32;                // n3*4 f32
  float* den  = a_d + n3 * 4;                 // n3*4 f32
  uint32_t* hgb = (uint32_t*)(den + n3 * 4);  // n3*16 uint (bf16x2)
  uint16_t* asb = (uint16_t*)(hgb + n3 * 16); // n3*4 ushort
  int* dir  = (int*)(asb + n3 * 4);           // 3*(NBPG+1)*NBLK ints
  int* bins = dir + (size_t)3 * (NBPG + 1) * NBLK;  // 3*NBLK*8192 ints

  k_detect<<<1, 256, 0, stream>>>(d_in[1], flag);
  k_node<<<(N + 255) / 256, 256, 0, stream>>>(
      d_in[0], d_in[1],
      d_in[5], d_in[6], d_in[7], d_in[8], d_in[9], d_in[10],
      d_in[11], d_in[12], d_in[13],
      d_in[15], d_in[16], d_in[17],
      d_in[19], d_in[20], d_in[21],
      flag, hgb, asb, a_d, den, agg, N);

  dim3 gbk((unsigned)NBLK, 3, 1);
  k_bin2<<<gbk, 256, 0, stream>>>(
      (const int*)d_in[2], (const int*)d_in[3], (const int*)d_in[4],
      dir, bins, NBPG, NBLK, E);

  const unsigned gsz = (unsigned)(8 * SLOTS);
  k_vgather<<<gsz, 256, 0, stream>>>(dir, bins, hgb, asb, a_d, den, agg,
                                     NBPG, NBLK, N, 0, mid);
  k_vgather<<<gsz, 256, 0, stream>>>(dir, bins, hgb, asb, a_d, den, agg,
                                     NBPG, NBLK, N, mid, N);

  k_final<<<(N + 255) / 256, 256, 0, stream>>>(
      den, agg, d_in[14], d_in[18], d_in[22],
      d_in[23], d_in[24], d_in[25], d_in[26], flag, d_out, N);
}

// Round 17
// 432.789 us; speedup vs baseline: 1.6078x; 1.6078x over previous
//
#include <hip/hip_runtime.h>
#include <hip/hip_bf16.h>
#include <stdint.h>

typedef __hip_bfloat16 bf16;

__device__ __forceinline__ float b2f(bf16 v){ return __bfloat162float(v); }

__device__ __forceinline__ uint16_t f2b(float x){           // RNE f32->bf16
  uint32_t u = __float_as_uint(x);
  return (uint16_t)((u + 0x7FFFu + ((u >> 16) & 1u)) >> 16);
}

#define DSTS_PER_BKT 128
#define BKT_SHIFT 7
#define CHUNKE 8192          // edges per bin block (BIN_IT*256)
#define CAP 8192             // LDS sort capacity (>= max single run = CHUNKE)
#define PPT 32               // payloads per thread in register permute (CAP/256)
#define BIN_IT 32            // edges per thread in bin pass
#define MAXB 1024            // max buckets per graph
#define NBLKMAX 512          // max edge-chunks per graph (E <= 4.19M)
#define ROWS_PER_WAVE (DSTS_PER_BKT / 4)

struct CvtTab {
  const void* src[24];
  int n[24];
  int off[24];
};

// ---------------------------------------------------------------------------
// Detect whether float inputs are bf16 (flag=1) or f32 (flag=0).
// ---------------------------------------------------------------------------
__global__ __launch_bounds__(256) void k_detect(const void* __restrict__ sample,
                                                int* __restrict__ flag)
{
  __shared__ int bad;
  if (threadIdx.x == 0) bad = 0;
  __syncthreads();
  const unsigned short* u = (const unsigned short*)sample;
  int lbad = 0;
  for (int k = threadIdx.x; k < 1024; k += 256) {
    unsigned short b = u[k];
    unsigned e = (b >> 7) & 0xFFu;
    if (e >= 141u || (e <= 90u && (b & 0x7FFFu) != 0)) lbad = 1;
  }
  if (lbad) atomicOr(&bad, 1);
  __syncthreads();
  if (threadIdx.x == 0) flag[0] = (bad == 0) ? 1 : 0;
}

// ---------------------------------------------------------------------------
__global__ __launch_bounds__(256) void k_convert(CvtTab tab, const int* __restrict__ flag,
                                                 float* __restrict__ dst, int total)
{
  const bool isb = (*flag) != 0;
  for (int t = blockIdx.x * 256 + threadIdx.x; t < total; t += gridDim.x * 256) {
    int a = 0;
    while (a < 23 && t >= tab.off[a] + tab.n[a]) ++a;
    int j = t - tab.off[a];
    float v = isb ? b2f(((const bf16*)tab.src[a])[j])
                  : ((const float*)tab.src[a])[j];
    dst[t] = v;
  }
}

// ---------------------------------------------------------------------------
// Per-node prep: f linears, h = f @ Wg, attention coefs, self-loop init of
// den/agg (f32), and the bf16 gather tables hgb (32x bf16 = 64B row) and
// asb (4x bf16). Softmax without max-shift (logits bounded -> identical).
// ---------------------------------------------------------------------------
__global__ __launch_bounds__(256) void k_node(
  const float* __restrict__ cFp, const float* __restrict__ cFa,
  const float* __restrict__ cWp, const float* __restrict__ cbp,
  const float* __restrict__ cWa, const float* __restrict__ cba,
  const float* __restrict__ cWs, const float* __restrict__ cbs,
  const float* __restrict__ cWg0, const float* __restrict__ cAs0, const float* __restrict__ cAd0,
  const float* __restrict__ cWg1, const float* __restrict__ cAs1, const float* __restrict__ cAd1,
  const float* __restrict__ cWg2, const float* __restrict__ cAs2, const float* __restrict__ cAd2,
  uint32_t* __restrict__ hgb, uint16_t* __restrict__ asb, float* __restrict__ a_d,
  float* __restrict__ den, float* __restrict__ agg, int N)
{
  __shared__ float sWs[14*32];
  __shared__ float sWp[3*32];
  __shared__ float sWa[11*32];
  __shared__ float sb[3][32];
  __shared__ float sWg[3][32*32];
  __shared__ float sA[3][2][32];
  const int tid = threadIdx.x;
  for (int t = tid; t < 14*32; t += 256) sWs[t] = cWs[t];
  for (int t = tid; t < 3*32;  t += 256) sWp[t] = cWp[t];
  for (int t = tid; t < 11*32; t += 256) sWa[t] = cWa[t];
  if (tid < 32) {
    sb[0][tid] = cbs[tid]; sb[1][tid] = cbp[tid]; sb[2][tid] = cba[tid];
    sA[0][0][tid] = cAs0[tid]; sA[0][1][tid] = cAd0[tid];
    sA[1][0][tid] = cAs1[tid]; sA[1][1][tid] = cAd1[tid];
    sA[2][0][tid] = cAs2[tid]; sA[2][1][tid] = cAd2[tid];
  }
  for (int t = tid; t < 32*32; t += 256) {
    sWg[0][t] = cWg0[t]; sWg[1][t] = cWg1[t]; sWg[2][t] = cWg2[t];
  }
  __syncthreads();

  const int i = blockIdx.x * 256 + tid;
  if (i >= N) return;

  float xp[3], xa[11];
  #pragma unroll
  for (int k = 0; k < 3; ++k)  xp[k] = cFp[i*3 + k];
  #pragma unroll
  for (int k = 0; k < 11; ++k) xa[k] = cFa[i*11 + k];

  for (int g = 0; g < 3; ++g) {
    float f[32];
    if (g == 0) {
      #pragma unroll
      for (int j = 0; j < 32; ++j) {
        float acc = sb[0][j];
        #pragma unroll
        for (int k = 0; k < 3; ++k)  acc += xp[k] * sWs[k*32 + j];
        #pragma unroll
        for (int k = 0; k < 11; ++k) acc += xa[k] * sWs[(3+k)*32 + j];
        f[j] = acc;
      }
    } else if (g == 1) {
      #pragma unroll
      for (int j = 0; j < 32; ++j) {
        float acc = sb[1][j];
        #pragma unroll
        for (int k = 0; k < 3; ++k) acc += xp[k] * sWp[k*32 + j];
        f[j] = acc;
      }
    } else {
      #pragma unroll
      for (int j = 0; j < 32; ++j) {
        float acc = sb[2][j];
        #pragma unroll
        for (int k = 0; k < 11; ++k) acc += xa[k] * sWa[k*32 + j];
        f[j] = acc;
      }
    }

    const float* Wg = sWg[g];
    float hv[32];
    #pragma unroll
    for (int j = 0; j < 32; ++j) {
      float acc = 0.f;
      #pragma unroll
      for (int k = 0; k < 32; ++k) acc += f[k] * Wg[k*32 + j];
      hv[j] = acc;
    }

    float asv[4], adv[4], exv[4];
    #pragma unroll
    for (int h = 0; h < 4; ++h) {
      float s0 = 0.f, s1 = 0.f;
      #pragma unroll
      for (int c = 0; c < 8; ++c) {
        s0 += hv[h*8 + c] * sA[g][0][h*8 + c];
        s1 += hv[h*8 + c] * sA[g][1][h*8 + c];
      }
      asv[h] = s0; adv[h] = s1;
      float e = s0 + s1;
      e = e > 0.f ? e : 0.2f * e;
      exv[h] = __expf(e);
    }

    const size_t row = (size_t)g * N + i;
    uint32_t* hp = hgb + row * 16;
    #pragma unroll
    for (int q = 0; q < 4; ++q) {
      uint4 u;
      u.x = (uint32_t)f2b(hv[q*8+0]) | ((uint32_t)f2b(hv[q*8+1]) << 16);
      u.y = (uint32_t)f2b(hv[q*8+2]) | ((uint32_t)f2b(hv[q*8+3]) << 16);
      u.z = (uint32_t)f2b(hv[q*8+4]) | ((uint32_t)f2b(hv[q*8+5]) << 16);
      u.w = (uint32_t)f2b(hv[q*8+6]) | ((uint32_t)f2b(hv[q*8+7]) << 16);
      *(uint4*)(hp + q*4) = u;
    }
    *(ushort4*)(asb + row * 4) =
        make_ushort4(f2b(asv[0]), f2b(asv[1]), f2b(asv[2]), f2b(asv[3]));

    float4* agp = (float4*)(agg + row * 32);
    #pragma unroll
    for (int q = 0; q < 8; ++q) {
      float ex = exv[q >> 1];
      agp[q] = make_float4(ex*hv[q*4+0], ex*hv[q*4+1], ex*hv[q*4+2], ex*hv[q*4+3]);
    }
    *(float4*)(a_d + row*4) = make_float4(adv[0], adv[1], adv[2], adv[3]);
    *(float4*)(den + row*4) = make_float4(exv[0], exv[1], exv[2], exv[3]);
  }
}

// ---------------------------------------------------------------------------
// Binning v2 — block-major, full-line writes only, zero global atomics.
// Each block sorts its 8192-edge chunk by bucket in LDS and writes it as one
// contiguous 32KB streaming store. Per-(bucket,block) offsets go to dir.
// ---------------------------------------------------------------------------
__global__ __launch_bounds__(256) void k_bin2(
  const int* __restrict__ ei0, const int* __restrict__ ei1, const int* __restrict__ ei2,
  int* __restrict__ dir, int* __restrict__ bins, int NBPG, int NBLK, int E)
{
  const int g = blockIdx.y;
  const int* __restrict__ ei = (g == 0) ? ei0 : (g == 1 ? ei1 : ei2);
  __shared__ int sp[CHUNKE];            // 32 KB staged payloads
  __shared__ int hist[MAXB];
  __shared__ int soff[MAXB + 1];
  __shared__ int s[256];
  const int tid = threadIdx.x;
  const int blk = blockIdx.x;
  const int base = blk * CHUNKE;
  const int m = min(CHUNKE, E - base);

  for (int t = tid; t < NBPG; t += 256) hist[t] = 0;
  __syncthreads();

  int pk[BIN_IT];
  #pragma unroll
  for (int k = 0; k < BIN_IT; ++k) {
    int idx = base + k * 256 + tid;
    if (idx < E) {
      int d = ei[E + idx];
      int b = d >> BKT_SHIFT;
      int loc = atomicAdd(&hist[b], 1);
      pk[k] = (b << 20) | (loc << 7) | (d & (DSTS_PER_BKT - 1));
    } else pk[k] = -1;
  }
  __syncthreads();

  // exclusive scan hist -> soff
  {
    const int sb = tid * 4;
    int v[4]; int sum = 0;
    #pragma unroll
    for (int j = 0; j < 4; ++j) {
      int i = sb + j; int x = (i < NBPG) ? hist[i] : 0; v[j] = x; sum += x;
    }
    s[tid] = sum;
    __syncthreads();
    for (int d = 1; d < 256; d <<= 1) {
      int t = (tid >= d) ? s[tid - d] : 0;
      __syncthreads();
      s[tid] += t;
      __syncthreads();
    }
    int run = s[tid] - sum;
    #pragma unroll
    for (int j = 0; j < 4; ++j) {
      int i = sb + j;
      if (i < NBPG) { soff[i] = run; run += v[j]; }
    }
    if (tid == 255) soff[NBPG] = s[255];
  }
  __syncthreads();

  for (int t = tid; t <= NBPG; t += 256)
    dir[((size_t)(g * (NBPG + 1) + t)) * NBLK + blk] = soff[t];

  #pragma unroll
  for (int k = 0; k < BIN_IT; ++k) {
    int p = pk[k];
    if (p >= 0) {
      int idx = base + k * 256 + tid;
      int src = ei[idx];
      int b   = p >> 20;
      int loc = (p >> 7) & 0x1FFF;
      int dl  = p & (DSTS_PER_BKT - 1);
      sp[soff[b] + loc] = (dl << 17) | src;
    }
  }
  __syncthreads();

  const size_t ob = ((size_t)(g * NBLK + blk)) << 13;
  for (int i = tid; i < m; i += 256) bins[ob + i] = sp[i];
}

// ---------------------------------------------------------------------------
// Sorted gather, single-read + register-permute (R13 best config):
// one block/bucket. Per chunk: fused copy+count pass stages runs LINEARLY
// into sorted[] while counting dl (bins read ONCE); scan; register permute
// to dl-sorted order; then the wave-per-row 16-edge gather.
// ---------------------------------------------------------------------------
__global__ __launch_bounds__(256, 4) void k_vgather(
  const int* __restrict__ dir, const int* __restrict__ bins,
  const uint32_t* __restrict__ hgb, const uint16_t* __restrict__ asb,
  const float* __restrict__ a_d,
  float* __restrict__ den, float* __restrict__ agg, int NBPG, int NBLK, int N)
{
  __shared__ int sorted[CAP];                // 32 KB (stage + final, in place)
  __shared__ int runbase[NBLKMAX];
  __shared__ int pbase[NBLKMAX + 1];
  __shared__ int soff[DSTS_PER_BKT + 1];
  __shared__ int scnt[DSTS_PER_BKT];
  __shared__ int sscan[DSTS_PER_BKT];
  __shared__ int s[256];
  __shared__ int schunk;
  const int g = blockIdx.y, b = blockIdx.x, tid = threadIdx.x;
  const int wave = tid >> 6;
  const int lane = tid & 63;
  const int sub  = lane >> 4;
  const int l16  = lane & 15;
  const int h    = l16 >> 2;
  const int grp16 = tid >> 4;      // 16 groups of 16 lanes (copy pass)
  const int ln16  = tid & 15;
  const size_t gbase = (size_t)g * N;
  const int dst0 = b * DSTS_PER_BKT;

  // --- setup: run directory for this bucket ---
  const int* d0 = dir + ((size_t)(g * (NBPG + 1) + b)) * NBLK;
  const int* d1 = d0 + NBLK;
  for (int t = tid; t < NBLK; t += 256) {
    int r0 = d0[t], r1 = d1[t];
    runbase[t] = ((g * NBLK + t) << 13) + r0;
    pbase[t] = r1 - r0;                       // temp: run lengths
  }
  __syncthreads();
  {
    int v0 = (2*tid     < NBLK) ? pbase[2*tid]     : 0;
    int v1 = (2*tid + 1 < NBLK) ? pbase[2*tid + 1] : 0;
    __syncthreads();
    int sum = v0 + v1; s[tid] = sum;
    __syncthreads();
    for (int d = 1; d < 256; d <<= 1) {
      int t = (tid >= d) ? s[tid - d] : 0;
      __syncthreads();
      s[tid] += t;
      __syncthreads();
    }
    int run = s[tid] - sum;
    if (2*tid     <= NBLK) pbase[2*tid]     = run;
    if (2*tid + 1 <= NBLK) pbase[2*tid + 1] = run + v0;
  }
  __syncthreads();
  const int ntot = pbase[NBLK];

  int rlo = 0;
  while (rlo < NBLK) {
    if (tid == 0) {
      if (rlo == 0 && ntot <= CAP) schunk = NBLK;
      else {
        int lim = pbase[rlo] + CAP;
        int hi = rlo + 1;                      // single run always fits (CHUNKE == CAP)
        while (hi < NBLK && pbase[hi + 1] <= lim) ++hi;
        schunk = hi;
      }
    }
    if (tid < DSTS_PER_BKT) scnt[tid] = 0;
    __syncthreads();
    const int rhi = schunk;
    const int pb0 = pbase[rlo];
    const int m = pbase[rhi] - pb0;

    // --- fused copy + count: bins read once, staged linearly ---
    for (int rr = rlo + grp16; rr < rhi; rr += 16) {
      const int l = pbase[rr + 1] - pbase[rr];
      const int gbb = runbase[rr];
      const int ldst = pbase[rr] - pb0;
      for (int i = ln16; i < l; i += 16) {
        int p = bins[gbb + i];
        sorted[ldst + i] = p;
        atomicAdd(&scnt[(p >> 17) & (DSTS_PER_BKT - 1)], 1);
      }
    }
    __syncthreads();
    // scan scnt -> soff
    if (tid < DSTS_PER_BKT) sscan[tid] = scnt[tid];
    __syncthreads();
    for (int d = 1; d < DSTS_PER_BKT; d <<= 1) {
      int t = 0;
      if (tid < DSTS_PER_BKT && tid >= d) t = sscan[tid - d];
      __syncthreads();
      if (tid < DSTS_PER_BKT) sscan[tid] += t;
      __syncthreads();
    }
    if (tid < DSTS_PER_BKT) {
      int ex = sscan[tid] - scnt[tid];
      soff[tid] = ex;
      scnt[tid] = ex;                          // scatter cursor
    }
    if (tid == 0) soff[DSTS_PER_BKT] = m;
    __syncthreads();
    // --- in-place permute via registers (static unroll -> VGPRs) ---
    int pv[PPT];
    #pragma unroll
    for (int k = 0; k < PPT; ++k) {
      int i = k * 256 + tid;
      pv[k] = (i < m) ? sorted[i] : -1;
    }
    __syncthreads();
    #pragma unroll
    for (int k = 0; k < PPT; ++k) {
      int p = pv[k];
      if (p >= 0) {
        int pos = atomicAdd(&scnt[(p >> 17) & (DSTS_PER_BKT - 1)], 1);
        sorted[pos] = p & 0x1FFFF;
      }
    }
    __syncthreads();

    // --- gather: wave-per-row, 16 edges in flight per step ---
    const int rbeg = wave * ROWS_PER_WAVE;
    for (int rl = rbeg; rl < rbeg + ROWS_PER_WAVE; ++rl) {
      const int dst = dst0 + rl;
      if (dst >= N) break;
      const int cs = soff[rl], ce = soff[rl + 1];
      const size_t row = gbase + dst;
      const float ad = a_d[row * 4 + h];
      float ax = 0.f, ay = 0.f, w = 0.f;
      for (int c = cs + sub; c < ce; c += 16) {
        const int i0 = c        < ce ? sorted[c]      : -1;
        const int i1 = (c + 4)  < ce ? sorted[c + 4]  : -1;
        const int i2 = (c + 8)  < ce ? sorted[c + 8]  : -1;
        const int i3 = (c + 12) < ce ? sorted[c + 12] : -1;
        const int p0 = i0 < 0 ? 0 : i0;
        const int p1 = i1 < 0 ? 0 : i1;
        const int p2 = i2 < 0 ? 0 : i2;
        const int p3 = i3 < 0 ? 0 : i3;
        const uint32_t u0 = hgb[(gbase + p0) * 16 + l16];
        const uint32_t u1 = hgb[(gbase + p1) * 16 + l16];
        const uint32_t u2 = hgb[(gbase + p2) * 16 + l16];
        const uint32_t u3 = hgb[(gbase + p3) * 16 + l16];
        const uint16_t t0 = asb[(gbase + p0) * 4 + h];
        const uint16_t t1 = asb[(gbase + p1) * 4 + h];
        const uint16_t t2 = asb[(gbase + p2) * 4 + h];
        const uint16_t t3 = asb[(gbase + p3) * 4 + h];
        float e0 = __uint_as_float((uint32_t)t0 << 16) + ad; e0 = e0 > 0.f ? e0 : 0.2f * e0;
        float e1 = __uint_as_float((uint32_t)t1 << 16) + ad; e1 = e1 > 0.f ? e1 : 0.2f * e1;
        float e2 = __uint_as_float((uint32_t)t2 << 16) + ad; e2 = e2 > 0.f ? e2 : 0.2f * e2;
        float e3 = __uint_as_float((uint32_t)t3 << 16) + ad; e3 = e3 > 0.f ? e3 : 0.2f * e3;
        const float w0 = i0 >= 0 ? __expf(e0) : 0.f;
        const float w1 = i1 >= 0 ? __expf(e1) : 0.f;
        const float w2 = i2 >= 0 ? __expf(e2) : 0.f;
        const float w3 = i3 >= 0 ? __expf(e3) : 0.f;
        ax += w0 * __uint_as_float(u0 << 16);
        ay += w0 * __uint_as_float(u0 & 0xFFFF0000u);
        ax += w1 * __uint_as_float(u1 << 16);
        ay += w1 * __uint_as_float(u1 & 0xFFFF0000u);
        ax += w2 * __uint_as_float(u2 << 16);
        ay += w2 * __uint_as_float(u2 & 0xFFFF0000u);
        ax += w3 * __uint_as_float(u3 << 16);
        ay += w3 * __uint_as_float(u3 & 0xFFFF0000u);
        w += w0 + w1 + w2 + w3;
      }
      ax += __shfl_xor(ax, 16); ay += __shfl_xor(ay, 16); w += __shfl_xor(w, 16);
      ax += __shfl_xor(ax, 32); ay += __shfl_xor(ay, 32); w += __shfl_xor(w, 32);
      if (sub == 0) {
        float2* ap = (float2*)(agg + row * 32) + l16;
        float2 sv = *ap;
        sv.x += ax; sv.y += ay;
        *ap = sv;
        if ((l16 & 3) == 0) den[row * 4 + h] += w;
      }
    }
    __syncthreads();
    rlo = rhi;
  }
}

// ---------------------------------------------------------------------------
// Final: normalize, +GAT bias, ELU, concat -> MLP -> output.
// ---------------------------------------------------------------------------
__global__ __launch_bounds__(256) void k_final(
  const float* __restrict__ den, const float* __restrict__ agg,
  const float* __restrict__ cbg0, const float* __restrict__ cbg1, const float* __restrict__ cbg2,
  const float* __restrict__ cW1, const float* __restrict__ cb1,
  const float* __restrict__ cW2, const float* __restrict__ cb2,
  const int* __restrict__ flag, void* __restrict__ out, int N)
{
  __shared__ float sW1[96*32];
  __shared__ float sW2[32*32];
  __shared__ float sb1[32], sb2[32], sbg[3][32];
  const int tid = threadIdx.x;
  for (int t = tid; t < 96*32; t += 256) sW1[t] = cW1[t];
  for (int t = tid; t < 32*32; t += 256) sW2[t] = cW2[t];
  if (tid < 32) {
    sb1[tid] = cb1[tid]; sb2[tid] = cb2[tid];
    sbg[0][tid] = cbg0[tid]; sbg[1][tid] = cbg1[tid]; sbg[2][tid] = cbg2[tid];
  }
  __syncthreads();

  const int i = blockIdx.x * 256 + tid;
  if (i >= N) return;

  float h96[96];
  #pragma unroll
  for (int g = 0; g < 3; ++g) {
    const size_t row = (size_t)g * N + i;
    float4 d4 = *(const float4*)(den + row * 4);
    float invs[4] = {1.f/d4.x, 1.f/d4.y, 1.f/d4.z, 1.f/d4.w};
    const float4* av = (const float4*)(agg + row * 32);
    #pragma unroll
    for (int q = 0; q < 8; ++q) {
      float4 a4 = av[q];
      float iv = invs[q >> 1];
      float vals[4] = {a4.x, a4.y, a4.z, a4.w};
      #pragma unroll
      for (int k = 0; k < 4; ++k) {
        float v = vals[k] * iv + sbg[g][q*4 + k];
        v = v > 0.f ? v : (__expf(v) - 1.f);
        h96[g*32 + q*4 + k] = v;
      }
    }
  }

  float h1[32];
  #pragma unroll
  for (int j = 0; j < 32; ++j) {
    float acc = sb1[j];
    #pragma unroll
    for (int k = 0; k < 96; ++k) acc += h96[k] * sW1[k*32 + j];
    h1[j] = acc > 0.f ? acc : 0.f;
  }

  const bool isb = (*flag) != 0;
  #pragma unroll
  for (int j = 0; j < 32; ++j) {
    float acc = sb2[j];
    #pragma unroll
    for (int k = 0; k < 32; ++k) acc += h1[k] * sW2[k*32 + j];
    if (isb) ((bf16*)out)[(size_t)i*32 + j] = __float2bfloat16(acc);
    else     ((float*)out)[(size_t)i*32 + j] = acc;
  }
}

// ---------------------------------------------------------------------------
extern "C" void kernel_launch(void* const* d_in, const int* in_sizes, int n_in,
                              void* d_out, int out_size, void* d_ws, size_t ws_size,
                              hipStream_t stream)
{
  const int N = in_sizes[0] / 3;     // F_p_raw is [N,3]
  const int E = in_sizes[2] / 2;     // edge_index is [2,E]
  const int NBPG = (N + DSTS_PER_BKT - 1) / DSTS_PER_BKT;
  const int NBLK = (E + CHUNKE - 1) / CHUNKE;

  float* ws  = (float*)d_ws;
  int* flag  = (int*)d_ws;
  float* cvt = ws + 64;

  static const int order[24] = {1, 0,
    5, 6, 7, 8, 9, 10,
    11, 12, 13, 14,
    15, 16, 17, 18,
    19, 20, 21, 22,
    23, 24, 25, 26};
  CvtTab tab;
  int off0 = 0;
  for (int a = 0; a < 24; ++a) {
    tab.src[a] = d_in[order[a]];
    tab.n[a]   = in_sizes[order[a]];
    tab.off[a] = off0;
    off0 += tab.n[a];
  }
  const int total = off0;

  float* P[24];
  for (int a = 0; a < 24; ++a) P[a] = cvt + tab.off[a];
  float *cFa = P[0],  *cFp = P[1];
  float *cWp = P[2],  *cbp = P[3],  *cWa = P[4],  *cba = P[5],  *cWs = P[6], *cbs = P[7];
  float *cWg0 = P[8],  *cAs0 = P[9],  *cAd0 = P[10], *cbg0 = P[11];
  float *cWg1 = P[12], *cAs1 = P[13], *cAd1 = P[14], *cbg1 = P[15];
  float *cWg2 = P[16], *cAs2 = P[17], *cAd2 = P[18], *cbg2 = P[19];
  float *cW1 = P[20], *cb1 = P[21], *cW2 = P[22], *cb2 = P[23];

  int pad = (4 - (total & 3)) & 3;
  float* big = cvt + total + pad;
  const size_t n3 = (size_t)3 * N;
  float* agg  = big;                          // n3*32 f32
  float* a_d  = agg + n3 * 32;                // n3*4 f32
  float* den  = a_d + n3 * 4;                 // n3*4 f32
  uint32_t* hgb = (uint32_t*)(den + n3 * 4);  // n3*16 uint (bf16x2)
  uint16_t* asb = (uint16_t*)(hgb + n3 * 16); // n3*4 ushort
  int* dir  = (int*)(asb + n3 * 4);           // 3*(NBPG+1)*NBLK ints
  int* bins = dir + (size_t)3 * (NBPG + 1) * NBLK;  // 3*NBLK*8192 ints

  k_detect<<<1, 256, 0, stream>>>(d_in[1], flag);
  k_convert<<<2048, 256, 0, stream>>>(tab, flag, cvt, total);
  k_node<<<(N + 255) / 256, 256, 0, stream>>>(
      cFp, cFa, cWp, cbp, cWa, cba, cWs, cbs,
      cWg0, cAs0, cAd0, cWg1, cAs1, cAd1, cWg2, cAs2, cAd2,
      hgb, asb, a_d, den, agg, N);

  dim3 gbk((unsigned)NBLK, 3, 1);
  k_bin2<<<gbk, 256, 0, stream>>>(
      (const int*)d_in[2], (const int*)d_in[3], (const int*)d_in[4],
      dir, bins, NBPG, NBLK, E);

  dim3 gg((unsigned)NBPG, 3, 1);
  k_vgather<<<gg, 256, 0, stream>>>(dir, bins, hgb, asb, a_d, den, agg, NBPG, NBLK, N);

  k_final<<<(N + 255) / 256, 256, 0, stream>>>(
      den, agg, cbg0, cbg1, cbg2, cW1, cb1, cW2, cb2, flag, d_out, N);
}